// Round 2
// baseline (1269.401 us; speedup 1.0000x reference)
//
#include <hip/hip_runtime.h>

typedef _Float16 f16;
typedef _Float16 f16x4 __attribute__((ext_vector_type(4)));
typedef _Float16 f16x8 __attribute__((ext_vector_type(8)));
typedef float f32x4 __attribute__((ext_vector_type(4)));
typedef float f32x16 __attribute__((ext_vector_type(16)));

#define MFMA32(A, B, C) __builtin_amdgcn_mfma_f32_32x32x16_f16(A, B, C, 0, 0, 0)
#define MFMA16(A, B, C) __builtin_amdgcn_mfma_f32_16x16x32_f16(A, B, C, 0, 0, 0)

constexpr int Bb = 4, Hh = 8, Ll = 2048, Dk = 64;
constexpr int Dm = 512;          // h*d_k channels
constexpr int LP = Ll + 4;       // padded time rows (t' = t + f, f in [0,4), pad 2 each side)
constexpr int BH = Bb * Hh;      // 32

// ---- workspace layout (bytes) ----
constexpr size_t OFF_FLAG = 0;                                   // int chosen_len
constexpr size_t NWT  = (size_t)Dm * Dm * 4;                     // elements per (tensor,hilo) weight
constexpr size_t OFF_WT   = 256;                                 // 4 * NWT f16
constexpr size_t NSTP = (size_t)Bb * LP * Dm;                    // elements per (tensor,hilo) STp
constexpr size_t OFF_STP  = OFF_WT + 4 * NWT * sizeof(f16);
constexpr size_t NQC  = (size_t)BH * Ll * Dk;                    // elements per (tensor,hilo) Qc/Kc
constexpr size_t OFF_QC   = OFF_STP + 4 * NSTP * sizeof(f16);
constexpr size_t OFF_VT   = OFF_QC + 4 * NQC * sizeof(f16);

// async global->LDS, 16B per lane; LDS dest must be wave-uniform-base + lane*16
__device__ __forceinline__ void gload_lds16(const void* g, void* l) {
    __builtin_amdgcn_global_load_lds((const __attribute__((address_space(1))) unsigned int*)g,
                                     (__attribute__((address_space(3))) unsigned int*)l, 16, 0, 0);
}

// ---------------- P1: mask + split conv weights into Wt[o][f*512+c] (hi/lo) ----------------
__global__ void kprep_w(const float* __restrict__ convq, const float* __restrict__ convk,
                        const float* __restrict__ w, int* __restrict__ flag,
                        f16* __restrict__ wtqh, f16* __restrict__ wtql,
                        f16* __restrict__ wtkh, f16* __restrict__ wtkl) {
    const int len = (4.f * w[1] > 2.f * w[0]) ? 4 : 2;   // argmax([2w0,4w1]) -> FILTER_LENGTHS[ind]
    if (blockIdx.x == 0 && blockIdx.y == 0 && threadIdx.x == 0) *flag = len;
    int tid = blockIdx.x * 256 + threadIdx.x;            // 0 .. 512*512-1
    int o = tid >> 9, c = tid & 511;
    const float* conv = blockIdx.y ? convk : convq;
    f16* dh = blockIdx.y ? wtkh : wtqh;
    f16* dl = blockIdx.y ? wtkl : wtql;
    const float4 v = *(const float4*)(conv + ((size_t)c * 512 + o) * 4);  // conv[c][o][0..3]
    float vv[4] = {v.x, v.y, v.z, v.w};
#pragma unroll
    for (int f = 0; f < 4; ++f) {
        float x = (f < len) ? vv[f] : 0.f;
        f16 hi = (f16)x;
        f16 lo = (f16)(x - (float)hi);
        size_t idx = (size_t)o * 2048 + (f << 9) + c;
        dh[idx] = hi; dl[idx] = lo;
    }
}

// ---------------- P2: transpose + split S (flat b x 512 x 2048 view of Q/K) into STp[b][t'][c] ----------------
__global__ void ktrans_s(const float* __restrict__ Q, const float* __restrict__ K,
                         f16* __restrict__ stqh, f16* __restrict__ stql,
                         f16* __restrict__ stkh, f16* __restrict__ stkl) {
    __shared__ float tile[64][65];
    int z = blockIdx.z;                 // tensor*4 + b
    int tensor = z >> 2, b = z & 3;
    const float* src = (tensor ? K : Q) + (size_t)b * Dm * Ll;
    f16* dh = (tensor ? stkh : stqh) + (size_t)b * LP * Dm;
    f16* dl = (tensor ? stkl : stql) + (size_t)b * LP * Dm;
    int j0 = blockIdx.x * 64, c0 = blockIdx.y * 64;
    int tl = threadIdx.x & 63, tg = threadIdx.x >> 6;
#pragma unroll
    for (int r = 0; r < 16; ++r) {
        int cl = (r << 2) + tg;
        int tabs = j0 + tl - 2;                          // STp[j] = S[:, j-2], zero-padded
        float v = (tabs >= 0 && tabs < Ll) ? src[(size_t)(c0 + cl) * Ll + tabs] : 0.f;
        tile[cl][tl] = v;
    }
    __syncthreads();
#pragma unroll
    for (int r = 0; r < 16; ++r) {
        int jl = (r << 2) + tg;
        int j = j0 + jl;
        if (j < LP) {
            float v = tile[tl][jl];
            f16 hi = (f16)v;
            f16 lo = (f16)(v - (float)hi);
            dh[(size_t)j * Dm + c0 + tl] = hi;
            dl[(size_t)j * Dm + c0 + tl] = lo;
        }
    }
}

// ---------------- P3: V -> Vt[bh][d][l] f16 ----------------
__global__ void ktrans_v(const float* __restrict__ V, f16* __restrict__ vt) {
    __shared__ float tile[64][65];
    int bh = blockIdx.y, l0 = blockIdx.x * 64;
    int tl = threadIdx.x & 63, tg = threadIdx.x >> 6;
    const float* src = V + (size_t)bh * Ll * Dk;
#pragma unroll
    for (int r = 0; r < 16; ++r) {
        int ll = (r << 2) + tg;
        tile[tl][ll] = src[(size_t)(l0 + ll) * Dk + tl];  // tl = d
    }
    __syncthreads();
#pragma unroll
    for (int r = 0; r < 16; ++r) {
        int dl = (r << 2) + tg;
        vt[((size_t)bh * Dk + dl) * Ll + l0 + tl] = (f16)tile[dl][tl];
    }
}

// ---------------- C: conv GEMM, LDS-staged 128x128 tile, BK=64, swizzled layout ----------------
// C[t][o] = sum_k A[t][k] B[k][o];  A[t][k=f*512+c] = STp[t+f][c];  B[k][o] = Wt[o][k]
__global__ __launch_bounds__(256, 2) void kconv(
    const float* __restrict__ Q, const float* __restrict__ K, const int* __restrict__ flag,
    const f16* __restrict__ stqh, const f16* __restrict__ stql,
    const f16* __restrict__ stkh, const f16* __restrict__ stkl,
    const f16* __restrict__ wtqh, const f16* __restrict__ wtql,
    const f16* __restrict__ wtkh, const f16* __restrict__ wtkl,
    f16* __restrict__ qch, f16* __restrict__ qcl,
    f16* __restrict__ kch, f16* __restrict__ kcl) {
    __shared__ f16 Ah[128 * 64], Al[128 * 64], Bh[128 * 64], Bl[128 * 64];  // 64 KB total
    int tensor = blockIdx.z, b = blockIdx.y;
    int tTile = blockIdx.x >> 2, oTile = blockIdx.x & 3;
    int tid = threadIdx.x;
    int wave = tid >> 6, lane = tid & 63;
    int wm = wave >> 1, wn = wave & 1;
    int lane31 = lane & 31, khalf = lane >> 5;
    int t0b = tTile * 128, o0b = oTile * 128;
    const f16* sh = (tensor ? stkh : stqh) + (size_t)b * LP * Dm;
    const f16* sl = (tensor ? stkl : stql) + (size_t)b * LP * Dm;
    const f16* wh = tensor ? wtkh : wtqh;
    const f16* wl = tensor ? wtkl : wtql;
    const float* src = (tensor ? K : Q) + (size_t)b * Hh * Ll * Dk;
    f16* dh = (tensor ? kch : qch) + (size_t)b * Hh * Ll * Dk;
    f16* dl = (tensor ? kcl : qcl) + (size_t)b * Hh * Ll * Dk;
    const float scale = tensor ? 1.f : 0.125f;           // fold 1/sqrt(d_k) into Qc exactly
    const int klen = (*flag) << 9;                       // 1024 or 2048

    f32x16 acc[2][2];
#pragma unroll
    for (int i = 0; i < 2; ++i)
#pragma unroll
        for (int j = 0; j < 2; ++j)
#pragma unroll
            for (int r = 0; r < 16; ++r) acc[i][j][r] = 0.f;

    for (int k0 = 0; k0 < klen; k0 += 64) {
        int f = k0 >> 9, c0 = k0 & 511;
        // stage A(hi/lo) rows [t0b+f, t0b+f+128) cols [c0,c0+64), B rows [o0b,o0b+128) cols [k0,k0+64)
        // LDS slot = linear; global column XOR-swizzled by row&7 so ds_read_b128 is conflict-free
#pragma unroll
        for (int it = 0; it < 4; ++it) {
            int slot = it * 256 + tid;
            int row = slot >> 3;
            int c16 = (slot & 7) ^ (row & 7);
            size_t ga = (size_t)(t0b + f + row) * Dm + c0 + c16 * 8;
            size_t gb = (size_t)(o0b + row) * 2048 + k0 + c16 * 8;
            gload_lds16(sh + ga, &Ah[slot * 8]);
            gload_lds16(sl + ga, &Al[slot * 8]);
            gload_lds16(wh + gb, &Bh[slot * 8]);
            gload_lds16(wl + gb, &Bl[slot * 8]);
        }
        __syncthreads();
#pragma unroll
        for (int kk = 0; kk < 4; ++kk) {
            f16x8 a_h[2], a_l[2], b_h[2], b_l[2];
            int cc = (kk << 1) + khalf;
#pragma unroll
            for (int i = 0; i < 2; ++i) {
                int row = wm * 64 + i * 32 + lane31;
                int c16 = cc ^ (row & 7);
                a_h[i] = *(const f16x8*)&Ah[row * 64 + c16 * 8];
                a_l[i] = *(const f16x8*)&Al[row * 64 + c16 * 8];
            }
#pragma unroll
            for (int j = 0; j < 2; ++j) {
                int row = wn * 64 + j * 32 + lane31;
                int c16 = cc ^ (row & 7);
                b_h[j] = *(const f16x8*)&Bh[row * 64 + c16 * 8];
                b_l[j] = *(const f16x8*)&Bl[row * 64 + c16 * 8];
            }
#pragma unroll
            for (int i = 0; i < 2; ++i)
#pragma unroll
                for (int j = 0; j < 2; ++j) {
                    acc[i][j] = MFMA32(a_h[i], b_h[j], acc[i][j]);
                    acc[i][j] = MFMA32(a_h[i], b_l[j], acc[i][j]);
                    acc[i][j] = MFMA32(a_l[i], b_h[j], acc[i][j]);
                }
        }
        __syncthreads();
    }
    // epilogue: C[t][o] -> (h,l,d) flat-reshape, add input, split to f16 hi/lo
#pragma unroll
    for (int i = 0; i < 2; ++i)
#pragma unroll
        for (int j = 0; j < 2; ++j)
#pragma unroll
            for (int r = 0; r < 16; ++r) {
                int trow = t0b + wm * 64 + i * 32 + (r & 3) + ((r >> 2) << 3) + (khalf << 2);
                int ocol = o0b + wn * 64 + j * 32 + lane31;
                int h = trow >> 8;
                int l = ((trow & 255) << 3) + (ocol >> 6);
                int d = ocol & 63;
                size_t idx = ((size_t)h * Ll + l) * Dk + d;
                float v2 = (acc[i][j][r] + src[idx]) * scale;
                f16 hi = (f16)v2;
                f16 lo = (f16)(v2 - (float)hi);
                dh[idx] = hi; dl[idx] = lo;
            }
}

// ---------------- F: fused scores -> softmax -> attn write + PV (16x16x32, 16 q-rows/wave) ----------------
__global__ __launch_bounds__(256, 4) void kattn(
    const f16* __restrict__ qch, const f16* __restrict__ qcl,
    const f16* __restrict__ kch, const f16* __restrict__ kcl,
    const f16* __restrict__ vt,
    float* __restrict__ ctx_out, float* __restrict__ attn_out) {
    __shared__ __align__(16) f16 ptile[4][16][40];       // 40: 80B rows -> conflict-free b128 reads
    int bh = blockIdx.y;
    int wave = threadIdx.x >> 6, lane = threadIdx.x & 63;
    int lane15 = lane & 15, quad = lane >> 4;
    int q0 = blockIdx.x * 64 + wave * 16;

    // resident Q fragments (hi/lo); d_k=64 -> 2 ksteps of 32
    f16x8 a_h[2], a_l[2];
    {
        size_t base = ((size_t)bh * Ll + q0 + lane15) * Dk + quad * 8;
        a_h[0] = *(const f16x8*)(qch + base);
        a_h[1] = *(const f16x8*)(qch + base + 32);
        a_l[0] = *(const f16x8*)(qcl + base);
        a_l[1] = *(const f16x8*)(qcl + base + 32);
    }
    float m[4], s[4];
#pragma unroll
    for (int r = 0; r < 4; ++r) { m[r] = -3.0e38f; s[r] = 0.f; }

    const size_t kb0 = (size_t)bh * Ll * Dk + quad * 8;

    // ---- pass 1: online row max + sumexp (1 exp per element) ----
    for (int ch = 0; ch < 128; ++ch) {
        size_t kb = kb0 + (size_t)(ch * 16 + lane15) * Dk;
        f16x8 kh0 = *(const f16x8*)(kch + kb);
        f16x8 kl0 = *(const f16x8*)(kcl + kb);
        f16x8 kh1 = *(const f16x8*)(kch + kb + 32);
        f16x8 kl1 = *(const f16x8*)(kcl + kb + 32);
        f32x4 acc = {0.f, 0.f, 0.f, 0.f};
        acc = MFMA16(a_h[0], kh0, acc);
        acc = MFMA16(a_h[0], kl0, acc);
        acc = MFMA16(a_l[0], kh0, acc);
        acc = MFMA16(a_h[1], kh1, acc);
        acc = MFMA16(a_h[1], kl1, acc);
        acc = MFMA16(a_l[1], kh1, acc);
#pragma unroll
        for (int r = 0; r < 4; ++r) {
            float v = acc[r];
            float d = v - m[r];
            float e = __expf(-fabsf(d));
            bool gt = d > 0.f;
            s[r] = gt ? __fmaf_rn(s[r], e, 1.f) : (s[r] + e);
            m[r] = gt ? v : m[r];
        }
    }
    // combine across the 16 lanes sharing each quad's rows
#pragma unroll
    for (int r = 0; r < 4; ++r) {
        float mm = m[r], ss = s[r];
#pragma unroll
        for (int off = 1; off < 16; off <<= 1) {
            float mo = __shfl_xor(mm, off, 64);
            float so = __shfl_xor(ss, off, 64);
            float mn = fmaxf(mm, mo);
            ss = ss * __expf(mm - mn) + so * __expf(mo - mn);
            mm = mn;
        }
        m[r] = mm;
        s[r] = 1.f / ss;   // inv_s
    }

    f32x4 ctx[4];
#pragma unroll
    for (int n = 0; n < 4; ++n) ctx[n] = (f32x4){0.f, 0.f, 0.f, 0.f};

    // ---- pass 2: recompute scores (identical MFMA order), write attn, accumulate PV ----
    for (int c2 = 0; c2 < 64; ++c2) {
#pragma unroll
        for (int sub = 0; sub < 2; ++sub) {
            int ch = c2 * 2 + sub;
            size_t kb = kb0 + (size_t)(ch * 16 + lane15) * Dk;
            f16x8 kh0 = *(const f16x8*)(kch + kb);
            f16x8 kl0 = *(const f16x8*)(kcl + kb);
            f16x8 kh1 = *(const f16x8*)(kch + kb + 32);
            f16x8 kl1 = *(const f16x8*)(kcl + kb + 32);
            f32x4 acc = {0.f, 0.f, 0.f, 0.f};
            acc = MFMA16(a_h[0], kh0, acc);
            acc = MFMA16(a_h[0], kl0, acc);
            acc = MFMA16(a_l[0], kh0, acc);
            acc = MFMA16(a_h[1], kh1, acc);
            acc = MFMA16(a_h[1], kl1, acc);
            acc = MFMA16(a_l[1], kh1, acc);
#pragma unroll
            for (int r = 0; r < 4; ++r) {
                float p = __expf(acc[r] - m[r]) * s[r];
                attn_out[((size_t)bh * Ll + q0 + quad * 4 + r) * Ll + ch * 16 + lane15] = p;
                ptile[wave][quad * 4 + r][sub * 16 + lane15] = (f16)p;
            }
        }
        __asm__ volatile("s_waitcnt lgkmcnt(0)" ::: "memory");  // wave-private LDS RAW
        f16x8 pa = *(const f16x8*)&ptile[wave][lane15][quad * 8];
#pragma unroll
        for (int n = 0; n < 4; ++n) {
            size_t vrow = ((size_t)bh * Dk + n * 16 + lane15) * Ll + c2 * 32 + quad * 8;
            f16x8 vb = *(const f16x8*)(vt + vrow);
            ctx[n] = MFMA16(pa, vb, ctx[n]);
        }
    }
#pragma unroll
    for (int n = 0; n < 4; ++n)
#pragma unroll
        for (int r = 0; r < 4; ++r)
            ctx_out[((size_t)bh * Ll + q0 + quad * 4 + r) * Dk + n * 16 + lane15] = ctx[n][r];
}

extern "C" void kernel_launch(void* const* d_in, const int* in_sizes, int n_in,
                              void* d_out, int out_size, void* d_ws, size_t ws_size,
                              hipStream_t stream) {
    const float* Q = (const float*)d_in[0];
    const float* K = (const float*)d_in[1];
    const float* V = (const float*)d_in[2];
    // d_in[3] = attn_mask (all-false, unused by the reference computation)
    const float* convq = (const float*)d_in[4];
    const float* convk = (const float*)d_in[5];
    const float* w = (const float*)d_in[6];

    char* ws = (char*)d_ws;
    int* flag = (int*)(ws + OFF_FLAG);
    f16* wtqh = (f16*)(ws + OFF_WT);
    f16* wtql = wtqh + NWT;
    f16* wtkh = wtql + NWT;
    f16* wtkl = wtkh + NWT;
    f16* stqh = (f16*)(ws + OFF_STP);
    f16* stql = stqh + NSTP;
    f16* stkh = stql + NSTP;
    f16* stkl = stkh + NSTP;
    f16* qch = (f16*)(ws + OFF_QC);
    f16* qcl = qch + NQC;
    f16* kch = qcl + NQC;
    f16* kcl = kch + NQC;
    f16* vt = (f16*)(ws + OFF_VT);

    float* ctx_out = (float*)d_out;
    float* attn_out = ctx_out + (size_t)BH * Ll * Dk;

    kprep_w<<<dim3(1024, 2), 256, 0, stream>>>(convq, convk, w, flag, wtqh, wtql, wtkh, wtkl);
    ktrans_s<<<dim3(33, 8, 8), 256, 0, stream>>>(Q, K, stqh, stql, stkh, stkl);
    ktrans_v<<<dim3(32, 32), 256, 0, stream>>>(V, vt);
    kconv<<<dim3(64, 4, 2), 256, 0, stream>>>(Q, K, flag, stqh, stql, stkh, stkl,
                                              wtqh, wtql, wtkh, wtkl, qch, qcl, kch, kcl);
    kattn<<<dim3(32, 32), 256, 0, stream>>>(qch, qcl, kch, kcl, vt, ctx_out, attn_out);
}

// Round 3
// 1133.407 us; speedup vs baseline: 1.1200x; 1.1200x over previous
//
#include <hip/hip_runtime.h>

typedef _Float16 f16;
typedef _Float16 f16x8 __attribute__((ext_vector_type(8)));
typedef float f32x16 __attribute__((ext_vector_type(16)));

#define MFMA32(A, B, C) __builtin_amdgcn_mfma_f32_32x32x16_f16(A, B, C, 0, 0, 0)

constexpr int Bb = 4, Hh = 8, Ll = 2048, Dk = 64, Dm = 512, BH = 32;

// element counts per (tensor,hilo) array
constexpr size_t NWF = (size_t)16 * 128 * 64 * 8;     // W frag-order: [ob16][k16:128][lane][8]
constexpr size_t NAF = (size_t)Bb * 64 * 128 * 64 * 8; // A frag-order: [b][tb64][k16:128][lane][8]
constexpr size_t NFF = (size_t)BH * 64 * 4 * 64 * 8;  // Qc/Kc frag-order: [bh][lb64][d16:4][lane][8]
constexpr size_t NVF = (size_t)BH * 2 * 128 * 64 * 8; // V frag-order: [bh][db2][l16:128][lane][8]

constexpr size_t OFF_WF = 256;
constexpr size_t OFF_AF = OFF_WF + 4 * NWF * sizeof(f16);
constexpr size_t OFF_FF = OFF_AF + 4 * NAF * sizeof(f16);
constexpr size_t OFF_VF = OFF_FF + 4 * NFF * sizeof(f16);

// ---------------- P1: mask + split conv weights into frag order ----------------
// W frag element: (ob,k16,lane,j) -> o = ob*32+(lane&31), k = k16*16+(lane>>5)*8+j, c=k&511, f=k>>9
__global__ void kprep_w(const float* __restrict__ convq, const float* __restrict__ convk,
                        const float* __restrict__ w, int* __restrict__ flag,
                        f16* __restrict__ wfhq, f16* __restrict__ wflq,
                        f16* __restrict__ wfhk, f16* __restrict__ wflk) {
    const int len = (4.f * w[1] > 2.f * w[0]) ? 4 : 2;   // argmax([2w0,4w1]) -> FILTER_LENGTHS[ind]
    if (blockIdx.x == 0 && blockIdx.y == 0 && threadIdx.x == 0) *flag = len;
    int tid = blockIdx.x * 256 + threadIdx.x;            // 0..262143 = c*512+o
    int o = tid & 511;
    const float* conv = blockIdx.y ? convk : convq;
    f16* dh = blockIdx.y ? wfhk : wfhq;
    f16* dl = blockIdx.y ? wflk : wflq;
    const float4 v = *(const float4*)(conv + (size_t)tid * 4);  // conv[c][o][0..3]
    float vv[4] = {v.x, v.y, v.z, v.w};
    int c = tid >> 9, ob = o >> 5;
#pragma unroll
    for (int f = 0; f < 4; ++f) {
        float x = (f < len) ? vv[f] : 0.f;
        f16 hi = (f16)x;
        f16 lo = (f16)(x - (float)hi);
        int k = (f << 9) + c;
        size_t idx = (((size_t)ob * 128 + (k >> 4)) * 64 + ((k >> 3) & 1) * 32 + (o & 31)) * 8 + (k & 7);
        dh[idx] = hi; dl[idx] = lo;
    }
}

// ---------------- P2: conv A operand, frag order, f-shift baked in ----------------
// A[t][k] = S[b][c][t+f-2] (zero pad), k=f*512+c. Block: one (tb, k16-group-of-4).
__global__ void kprep_a(const float* __restrict__ Q, const float* __restrict__ K,
                        const int* __restrict__ flag,
                        f16* __restrict__ afhq, f16* __restrict__ aflq,
                        f16* __restrict__ afhk, f16* __restrict__ aflk) {
    __shared__ float tile[64][36];
    int tensor = blockIdx.z, b = blockIdx.y;
    int tb = blockIdx.x >> 5, k16g = blockIdx.x & 31;
    int f = k16g >> 3;                       // constant over the block's 64 k's
    if (f >= *flag) return;                  // masked f: weights are zero and kconv never reads
    int c0 = (k16g * 64) & 511;
    const float* S = (tensor ? K : Q) + (size_t)b * Dm * Ll;  // flat b x 512 x 2048 view
    int tid = threadIdx.x;
    int t0 = tb * 32;
    // stage S[c0..c0+64)[t0-2 .. t0+34) -> 64x36 floats, row-major coalesced
#pragma unroll
    for (int i = 0; i < 9; ++i) {
        int e = i * 256 + tid;               // 0..2303
        int row = e / 36, col = e - row * 36;
        int t = t0 - 2 + col;
        tile[row][col] = (t >= 0 && t < Ll) ? S[(size_t)(c0 + row) * Ll + t] : 0.f;
    }
    __syncthreads();
    int sub = tid >> 6, lane = tid & 63;
    int k16 = k16g * 4 + sub;
    int khalf = lane >> 5, lane31 = lane & 31;
    f16x8 hv, lv;
#pragma unroll
    for (int j = 0; j < 8; ++j) {
        int cl = sub * 16 + khalf * 8 + j;   // c - c0
        float x = tile[cl][lane31 + f];      // t = t0+lane31, col index = lane31+f
        f16 hi = (f16)x;
        hv[j] = hi; lv[j] = (f16)(x - (float)hi);
    }
    f16* dh = tensor ? afhk : afhq;
    f16* dl = tensor ? aflk : aflq;
    size_t idx = ((((size_t)b * 64 + tb) * 128 + k16) * 64 + lane) * 8;
    *(f16x8*)(dh + idx) = hv;
    *(f16x8*)(dl + idx) = lv;
}

// ---------------- P3: V -> frag order for PV B-operand ----------------
// Vf element: (bh,db,l16,lane,j) -> d = db*32+(lane&31), l = l16*16+(lane>>5)*8+j
__global__ void kprep_v(const float* __restrict__ V, f16* __restrict__ vf) {
    int bh = blockIdx.y, l0 = blockIdx.x * 128;
    int tid = threadIdx.x;
    const float* src = V + (size_t)bh * Ll * Dk;
#pragma unroll
    for (int s = 0; s < 4; ++s) {
        int g = s * 4 + (tid >> 6);          // 0..15
        int lane = tid & 63;
        int l16s = g >> 1, db = g & 1;
        int khalf = lane >> 5, lane31 = lane & 31;
        int d = db * 32 + lane31;
        f16x8 out;
#pragma unroll
        for (int j = 0; j < 8; ++j) {
            int l = l0 + l16s * 16 + khalf * 8 + j;
            out[j] = (f16)src[(size_t)l * Dk + d];   // 128B runs across lanes
        }
        size_t idx = ((((size_t)bh * 2 + db) * 128 + (l0 >> 4) + l16s) * 64 + lane) * 8;
        *(f16x8*)(vf + idx) = out;
    }
}

// ---------------- C: conv GEMM, no LDS, all frag loads contiguous 1KB/wave ----------------
__global__ __launch_bounds__(256, 2) void kconv(
    const float* __restrict__ Q, const float* __restrict__ K, const int* __restrict__ flag,
    const f16* __restrict__ afhq, const f16* __restrict__ aflq,
    const f16* __restrict__ afhk, const f16* __restrict__ aflk,
    const f16* __restrict__ wfhq, const f16* __restrict__ wflq,
    const f16* __restrict__ wfhk, const f16* __restrict__ wflk,
    f16* __restrict__ ffhq, f16* __restrict__ fflq,
    f16* __restrict__ ffhk, f16* __restrict__ fflk) {
    int tensor = blockIdx.z, b = blockIdx.y;
    int tTile = blockIdx.x >> 2, oTile = blockIdx.x & 3;
    int wave = threadIdx.x >> 6, lane = threadIdx.x & 63;
    int wm = wave >> 1, wn = wave & 1;
    int lane31 = lane & 31, khalf = lane >> 5;
    const f16* ah = (tensor ? afhk : afhq) + ((size_t)(b * 64 + tTile * 4 + wm * 2) * 128) * 512;
    const f16* al = (tensor ? aflk : aflq) + ((size_t)(b * 64 + tTile * 4 + wm * 2) * 128) * 512;
    const f16* bh_ = (tensor ? wfhk : wfhq) + ((size_t)(oTile * 4 + wn * 2) * 128) * 512;
    const f16* bl_ = (tensor ? wflk : wflq) + ((size_t)(oTile * 4 + wn * 2) * 128) * 512;
    const float* src = (tensor ? K : Q) + (size_t)b * Hh * Ll * Dk;
    f16* dh = (tensor ? ffhk : ffhq);
    f16* dl = (tensor ? fflk : fflq);
    const float scale = tensor ? 1.f : 0.125f;          // fold 1/sqrt(d_k) into Qc exactly
    const int klen16 = (*flag) << 5;                    // 128 or 64

    f32x16 acc[2][2];
#pragma unroll
    for (int i = 0; i < 2; ++i)
#pragma unroll
        for (int j = 0; j < 2; ++j)
#pragma unroll
            for (int r = 0; r < 16; ++r) acc[i][j][r] = 0.f;

#pragma unroll 2
    for (int k16 = 0; k16 < klen16; ++k16) {
        f16x8 a_h[2], a_l[2], b_h[2], b_l[2];
#pragma unroll
        for (int i = 0; i < 2; ++i) {
            size_t off = ((size_t)(i * 128 + k16) * 64 + lane) * 8;
            a_h[i] = *(const f16x8*)(ah + off);
            a_l[i] = *(const f16x8*)(al + off);
        }
#pragma unroll
        for (int j = 0; j < 2; ++j) {
            size_t off = ((size_t)(j * 128 + k16) * 64 + lane) * 8;
            b_h[j] = *(const f16x8*)(bh_ + off);
            b_l[j] = *(const f16x8*)(bl_ + off);
        }
#pragma unroll
        for (int i = 0; i < 2; ++i)
#pragma unroll
            for (int j = 0; j < 2; ++j) {
                acc[i][j] = MFMA32(a_h[i], b_h[j], acc[i][j]);
                acc[i][j] = MFMA32(a_h[i], b_l[j], acc[i][j]);
                acc[i][j] = MFMA32(a_l[i], b_h[j], acc[i][j]);
            }
    }
    // epilogue: C[t][o] -> flat (h,l,d), add residual, scale, split, store in kattn frag order
#pragma unroll
    for (int i = 0; i < 2; ++i)
#pragma unroll
        for (int j = 0; j < 2; ++j)
#pragma unroll
            for (int r = 0; r < 16; ++r) {
                int trow = tTile * 128 + wm * 64 + i * 32 + (r & 3) + ((r >> 2) << 3) + (khalf << 2);
                int ocol = oTile * 128 + wn * 64 + j * 32 + lane31;
                int h = trow >> 8;
                int l = ((trow & 255) << 3) + (ocol >> 6);
                int d = ocol & 63;
                float v2 = (acc[i][j][r] + src[((size_t)h * Ll + l) * Dk + d]) * scale;
                f16 hi = (f16)v2;
                f16 lo = (f16)(v2 - (float)hi);
                size_t idx = ((((size_t)(b * 8 + h) * 64 + (l >> 5)) * 4 + (d >> 4)) * 64
                              + ((d >> 3) & 1) * 32 + (l & 31)) * 8 + (d & 7);
                dh[idx] = hi; dl[idx] = lo;
            }
}

// ---------------- F: fused scores -> softmax -> attn write + PV ----------------
__global__ __launch_bounds__(256, 2) void kattn(
    const f16* __restrict__ qfh, const f16* __restrict__ qfl,
    const f16* __restrict__ kfh, const f16* __restrict__ kfl,
    const f16* __restrict__ vf,
    float* __restrict__ ctx_out, float* __restrict__ attn_out) {
    __shared__ __align__(16) f16 ptile[4][32][36];
    int id = blockIdx.x;                        // 512; group 4 bh per XCD (id%8 ~ XCD)
    int bh = (id & 7) * 4 + (id >> 7);
    int qtile = (id >> 3) & 15;
    int wave = threadIdx.x >> 6, lane = threadIdx.x & 63;
    int lane31 = lane & 31, khalf = lane >> 5;
    int q0 = qtile * 128 + wave * 32;

    // resident Q fragments (hi/lo), 4 ksteps of 16 over d_k=64 — contiguous 1KB loads
    f16x8 a_h[4], a_l[4];
    {
        size_t qb = ((size_t)bh * 64 + (q0 >> 5)) * 4;
#pragma unroll
        for (int ks = 0; ks < 4; ++ks) {
            a_h[ks] = *(const f16x8*)(qfh + ((qb + ks) * 64 + lane) * 8);
            a_l[ks] = *(const f16x8*)(qfl + ((qb + ks) * 64 + lane) * 8);
        }
    }
    const f16* kbh = kfh + (size_t)bh * 64 * 4 * 512;
    const f16* kbl = kfl + (size_t)bh * 64 * 4 * 512;

    float m[16], s[16];
#pragma unroll
    for (int r = 0; r < 16; ++r) { m[r] = -3.0e38f; s[r] = 0.f; }

    // ---- pass 1: online row max + sumexp ----
#pragma unroll 2
    for (int ch = 0; ch < 64; ++ch) {
        f32x16 acc;
#pragma unroll
        for (int r = 0; r < 16; ++r) acc[r] = 0.f;
#pragma unroll
        for (int ks = 0; ks < 4; ++ks) {
            size_t off = (((size_t)ch * 4 + ks) * 64 + lane) * 8;
            f16x8 kh8 = *(const f16x8*)(kbh + off);
            f16x8 kl8 = *(const f16x8*)(kbl + off);
            acc = MFMA32(a_h[ks], kh8, acc);
            acc = MFMA32(a_h[ks], kl8, acc);
            acc = MFMA32(a_l[ks], kh8, acc);
        }
#pragma unroll
        for (int r = 0; r < 16; ++r) {
            float v = acc[r];
            float d = v - m[r];
            float e = __expf(-fabsf(d));
            bool gt = d > 0.f;
            s[r] = gt ? __fmaf_rn(s[r], e, 1.f) : (s[r] + e);
            m[r] = gt ? v : m[r];
        }
    }
    // combine across the 32 lanes of each half (rows are per-half in MFMA32 C-layout)
#pragma unroll
    for (int r = 0; r < 16; ++r) {
        float mm = m[r], ss = s[r];
#pragma unroll
        for (int off = 1; off < 32; off <<= 1) {
            float mo = __shfl_xor(mm, off, 64);
            float so = __shfl_xor(ss, off, 64);
            float mn = fmaxf(mm, mo);
            ss = ss * __expf(mm - mn) + so * __expf(mo - mn);
            mm = mn;
        }
        m[r] = mm;
        s[r] = 1.f / ss;   // inv sum
    }

    f32x16 ctx[2];
#pragma unroll
    for (int n = 0; n < 2; ++n)
#pragma unroll
        for (int r = 0; r < 16; ++r) ctx[n][r] = 0.f;

    // ---- pass 2: recompute scores (identical op order), write attn, accumulate PV ----
#pragma unroll 2
    for (int ch = 0; ch < 64; ++ch) {
        f32x16 acc;
#pragma unroll
        for (int r = 0; r < 16; ++r) acc[r] = 0.f;
#pragma unroll
        for (int ks = 0; ks < 4; ++ks) {
            size_t off = (((size_t)ch * 4 + ks) * 64 + lane) * 8;
            f16x8 kh8 = *(const f16x8*)(kbh + off);
            f16x8 kl8 = *(const f16x8*)(kbl + off);
            acc = MFMA32(a_h[ks], kh8, acc);
            acc = MFMA32(a_h[ks], kl8, acc);
            acc = MFMA32(a_l[ks], kh8, acc);
        }
#pragma unroll
        for (int r = 0; r < 16; ++r) {
            float p = __expf(acc[r] - m[r]) * s[r];
            int row = (r & 3) + ((r >> 2) << 3) + (khalf << 2);
            attn_out[((size_t)bh * Ll + q0 + row) * Ll + ch * 32 + lane31] = p;
            ptile[wave][row][lane31] = (f16)p;
        }
        __asm__ volatile("s_waitcnt lgkmcnt(0)" ::: "memory");  // wave-private LDS RAW
#pragma unroll
        for (int ks2 = 0; ks2 < 2; ++ks2) {
            f16x8 pa = *(const f16x8*)&ptile[wave][lane31][ks2 * 16 + khalf * 8];
#pragma unroll
            for (int n = 0; n < 2; ++n) {
                size_t off = ((((size_t)bh * 2 + n) * 128 + ch * 2 + ks2) * 64 + lane) * 8;
                f16x8 vb = *(const f16x8*)(vf + off);
                ctx[n] = MFMA32(pa, vb, ctx[n]);
            }
        }
    }
#pragma unroll
    for (int n = 0; n < 2; ++n)
#pragma unroll
        for (int r = 0; r < 16; ++r) {
            int row = (r & 3) + ((r >> 2) << 3) + (khalf << 2);
            ctx_out[((size_t)bh * Ll + q0 + row) * Dk + n * 32 + lane31] = ctx[n][r];
        }
}

extern "C" void kernel_launch(void* const* d_in, const int* in_sizes, int n_in,
                              void* d_out, int out_size, void* d_ws, size_t ws_size,
                              hipStream_t stream) {
    const float* Q = (const float*)d_in[0];
    const float* K = (const float*)d_in[1];
    const float* V = (const float*)d_in[2];
    // d_in[3] = attn_mask (all-false, unused)
    const float* convq = (const float*)d_in[4];
    const float* convk = (const float*)d_in[5];
    const float* w = (const float*)d_in[6];

    char* ws = (char*)d_ws;
    int* flag = (int*)ws;
    f16* wfhq = (f16*)(ws + OFF_WF);
    f16* wflq = wfhq + NWF;
    f16* wfhk = wflq + NWF;
    f16* wflk = wfhk + NWF;
    f16* afhq = (f16*)(ws + OFF_AF);
    f16* aflq = afhq + NAF;
    f16* afhk = aflq + NAF;
    f16* aflk = afhk + NAF;
    f16* ffhq = (f16*)(ws + OFF_FF);
    f16* fflq = ffhq + NFF;
    f16* ffhk = fflq + NFF;
    f16* fflk = ffhk + NFF;
    f16* vf = (f16*)(ws + OFF_VF);

    float* ctx_out = (float*)d_out;
    float* attn_out = ctx_out + (size_t)BH * Ll * Dk;

    kprep_w<<<dim3(1024, 2), 256, 0, stream>>>(convq, convk, w, flag, wfhq, wflq, wfhk, wflk);
    kprep_v<<<dim3(16, 32), 256, 0, stream>>>(V, vf);
    kprep_a<<<dim3(2048, 4, 2), 256, 0, stream>>>(Q, K, flag, afhq, aflq, afhk, aflk);
    kconv<<<dim3(64, 4, 2), 256, 0, stream>>>(Q, K, flag, afhq, aflq, afhk, aflk,
                                              wfhq, wflq, wfhk, wflk, ffhq, fflq, ffhk, fflk);
    kattn<<<dim3(512), 256, 0, stream>>>(ffhq, fflq, ffhk, fflk, vf, ctx_out, attn_out);
}

// Round 4
// 1066.140 us; speedup vs baseline: 1.1907x; 1.0631x over previous
//
#include <hip/hip_runtime.h>

typedef _Float16 f16;
typedef _Float16 f16x8 __attribute__((ext_vector_type(8)));
typedef float f32x16 __attribute__((ext_vector_type(16)));

#define MFMA32(A, B, C) __builtin_amdgcn_mfma_f32_32x32x16_f16(A, B, C, 0, 0, 0)

constexpr int Bb = 4, Hh = 8, Ll = 2048, Dk = 64, Dm = 512, BH = 32;

// element counts per (tensor,hilo) array
constexpr size_t NWF = (size_t)16 * 128 * 64 * 8;      // W frag: [ob16][k16:128][lane][8]
constexpr size_t NAF = (size_t)Bb * 64 * 128 * 64 * 8; // A frag: [b][tb64][k16:128][lane][8]
constexpr size_t NFF = (size_t)BH * 64 * 4 * 64 * 8;   // Qc/Kc frag: [bh][lb64][d16:4][lane][8]
constexpr size_t NVF = (size_t)BH * 2 * 128 * 64 * 8;  // V frag: [bh][db2][l16:128][lane][8]

constexpr size_t OFF_WF = 256;
constexpr size_t OFF_AF = OFF_WF + 4 * NWF * sizeof(f16);
constexpr size_t OFF_FF = OFF_AF + 4 * NAF * sizeof(f16);
constexpr size_t OFF_VF = OFF_FF + 4 * NFF * sizeof(f16);

// scores computed in base-2: fold log2(e)/sqrt(64) into Qc (exact softmax identity)
#define QSCALE 0.1803368801111204f

// ---------------- P1: mask + split conv weights into frag order ----------------
__global__ void kprep_w(const float* __restrict__ convq, const float* __restrict__ convk,
                        const float* __restrict__ w, int* __restrict__ flag,
                        f16* __restrict__ wfhq, f16* __restrict__ wflq,
                        f16* __restrict__ wfhk, f16* __restrict__ wflk) {
    const int len = (4.f * w[1] > 2.f * w[0]) ? 4 : 2;   // argmax([2w0,4w1]) -> FILTER_LENGTHS[ind]
    if (blockIdx.x == 0 && blockIdx.y == 0 && threadIdx.x == 0) *flag = len;
    int tid = blockIdx.x * 256 + threadIdx.x;            // 0..262143 = c*512+o
    int o = tid & 511;
    const float* conv = blockIdx.y ? convk : convq;
    f16* dh = blockIdx.y ? wfhk : wfhq;
    f16* dl = blockIdx.y ? wflk : wflq;
    const float4 v = *(const float4*)(conv + (size_t)tid * 4);  // conv[c][o][0..3]
    float vv[4] = {v.x, v.y, v.z, v.w};
    int c = tid >> 9, ob = o >> 5;
#pragma unroll
    for (int f = 0; f < 4; ++f) {
        float x = (f < len) ? vv[f] : 0.f;
        f16 hi = (f16)x;
        f16 lo = (f16)(x - (float)hi);
        int k = (f << 9) + c;
        size_t idx = (((size_t)ob * 128 + (k >> 4)) * 64 + ((k >> 3) & 1) * 32 + (o & 31)) * 8 + (k & 7);
        dh[idx] = hi; dl[idx] = lo;
    }
}

// ---------------- P2: conv A operand, frag order, f-shift baked in ----------------
__global__ void kprep_a(const float* __restrict__ Q, const float* __restrict__ K,
                        const int* __restrict__ flag,
                        f16* __restrict__ afhq, f16* __restrict__ aflq,
                        f16* __restrict__ afhk, f16* __restrict__ aflk) {
    __shared__ float tile[64][36];
    int tensor = blockIdx.z, b = blockIdx.y;
    int tb = blockIdx.x >> 5, k16g = blockIdx.x & 31;
    int f = k16g >> 3;                       // constant over the block's 64 k's
    if (f >= *flag) return;                  // masked f: weights are zero and kconv never reads
    int c0 = (k16g * 64) & 511;
    const float* S = (tensor ? K : Q) + (size_t)b * Dm * Ll;  // flat b x 512 x 2048 view
    int tid = threadIdx.x;
    int t0 = tb * 32;
#pragma unroll
    for (int i = 0; i < 9; ++i) {
        int e = i * 256 + tid;               // 0..2303
        int row = e / 36, col = e - row * 36;
        int t = t0 - 2 + col;
        tile[row][col] = (t >= 0 && t < Ll) ? S[(size_t)(c0 + row) * Ll + t] : 0.f;
    }
    __syncthreads();
    int sub = tid >> 6, lane = tid & 63;
    int k16 = k16g * 4 + sub;
    int khalf = lane >> 5, lane31 = lane & 31;
    f16x8 hv, lv;
#pragma unroll
    for (int j = 0; j < 8; ++j) {
        int cl = sub * 16 + khalf * 8 + j;
        float x = tile[cl][lane31 + f];
        f16 hi = (f16)x;
        hv[j] = hi; lv[j] = (f16)(x - (float)hi);
    }
    f16* dh = tensor ? afhk : afhq;
    f16* dl = tensor ? aflk : aflq;
    size_t idx = ((((size_t)b * 64 + tb) * 128 + k16) * 64 + lane) * 8;
    *(f16x8*)(dh + idx) = hv;
    *(f16x8*)(dl + idx) = lv;
}

// ---------------- P3: V -> frag order for PV B-operand ----------------
__global__ void kprep_v(const float* __restrict__ V, f16* __restrict__ vf) {
    int bh = blockIdx.y, l0 = blockIdx.x * 128;
    int tid = threadIdx.x;
    const float* src = V + (size_t)bh * Ll * Dk;
#pragma unroll
    for (int s = 0; s < 4; ++s) {
        int g = s * 4 + (tid >> 6);
        int lane = tid & 63;
        int l16s = g >> 1, db = g & 1;
        int khalf = lane >> 5, lane31 = lane & 31;
        int d = db * 32 + lane31;
        f16x8 out;
#pragma unroll
        for (int j = 0; j < 8; ++j) {
            int l = l0 + l16s * 16 + khalf * 8 + j;
            out[j] = (f16)src[(size_t)l * Dk + d];
        }
        size_t idx = ((((size_t)bh * 2 + db) * 128 + (l0 >> 4) + l16s) * 64 + lane) * 8;
        *(f16x8*)(vf + idx) = out;
    }
}

// ---------------- C: conv GEMM, 1024 blocks, ping-pong pipelined frag loads ----------------
__global__ __launch_bounds__(256, 4) void kconv(
    const float* __restrict__ Q, const float* __restrict__ K, const int* __restrict__ flag,
    const f16* __restrict__ afhq, const f16* __restrict__ aflq,
    const f16* __restrict__ afhk, const f16* __restrict__ aflk,
    const f16* __restrict__ wfhq, const f16* __restrict__ wflq,
    const f16* __restrict__ wfhk, const f16* __restrict__ wflk,
    f16* __restrict__ ffhq, f16* __restrict__ fflq,
    f16* __restrict__ ffhk, f16* __restrict__ fflk) {
    int id = blockIdx.x;                        // XCD swizzle: 4 oTile-siblings share id&7
    int xcd = id & 7, oTile = (id >> 3) & 3, gidx = id >> 5;
    int g = gidx * 8 + xcd;
    int tt = g & 31, b = (g >> 5) & 3, tensor = (g >> 7) & 1;
    int wave = threadIdx.x >> 6, lane = threadIdx.x & 63;
    int wn = wave & 1, wm = wave >> 1;
    int lane31 = lane & 31, khalf = lane >> 5;
    const f16* ah = (tensor ? afhk : afhq) + ((size_t)(b * 64 + tt * 2 + wm) * 128) * 512;
    const f16* al = (tensor ? aflk : aflq) + ((size_t)(b * 64 + tt * 2 + wm) * 128) * 512;
    const f16* bhp = (tensor ? wfhk : wfhq) + ((size_t)(oTile * 4 + wn * 2) * 128) * 512;
    const f16* blp = (tensor ? wflk : wflq) + ((size_t)(oTile * 4 + wn * 2) * 128) * 512;
    const float* src = (tensor ? K : Q) + (size_t)b * Hh * Ll * Dk;
    f16* dh = (tensor ? ffhk : ffhq);
    f16* dl = (tensor ? fflk : fflq);
    const float scale = tensor ? 1.f : QSCALE;
    const int klen16 = (*flag) << 5;            // 128 or 64 (even)

    f32x16 acc[2];
#pragma unroll
    for (int j = 0; j < 2; ++j)
#pragma unroll
        for (int r = 0; r < 16; ++r) acc[j][r] = 0.f;

    f16x8 Aah, Aal, Abh[2], Abl[2];             // buffer A
    f16x8 Bah, Bal, Bbh[2], Bbl[2];             // buffer B
    const size_t lo8 = (size_t)lane * 8;

    // prime buffer A with k16=0
    Aah = *(const f16x8*)(ah + lo8);
    Aal = *(const f16x8*)(al + lo8);
    Abh[0] = *(const f16x8*)(bhp + lo8);
    Abl[0] = *(const f16x8*)(blp + lo8);
    Abh[1] = *(const f16x8*)(bhp + 128 * 512 + lo8);
    Abl[1] = *(const f16x8*)(blp + 128 * 512 + lo8);

    for (int k16 = 0; k16 < klen16; k16 += 2) {
        {   // prefetch k16+1 into B
            int kn = k16 + 1 < klen16 ? k16 + 1 : k16;
            size_t o = (size_t)kn * 512 + lo8;
            Bah = *(const f16x8*)(ah + o);
            Bal = *(const f16x8*)(al + o);
            Bbh[0] = *(const f16x8*)(bhp + o);
            Bbl[0] = *(const f16x8*)(blp + o);
            Bbh[1] = *(const f16x8*)(bhp + 128 * 512 + o);
            Bbl[1] = *(const f16x8*)(blp + 128 * 512 + o);
        }
#pragma unroll
        for (int j = 0; j < 2; ++j) {
            acc[j] = MFMA32(Aah, Abh[j], acc[j]);
            acc[j] = MFMA32(Aah, Abl[j], acc[j]);
            acc[j] = MFMA32(Aal, Abh[j], acc[j]);
        }
        {   // prefetch k16+2 into A
            int kn = k16 + 2 < klen16 ? k16 + 2 : klen16 - 1;
            size_t o = (size_t)kn * 512 + lo8;
            Aah = *(const f16x8*)(ah + o);
            Aal = *(const f16x8*)(al + o);
            Abh[0] = *(const f16x8*)(bhp + o);
            Abl[0] = *(const f16x8*)(blp + o);
            Abh[1] = *(const f16x8*)(bhp + 128 * 512 + o);
            Abl[1] = *(const f16x8*)(blp + 128 * 512 + o);
        }
#pragma unroll
        for (int j = 0; j < 2; ++j) {
            acc[j] = MFMA32(Bah, Bbh[j], acc[j]);
            acc[j] = MFMA32(Bah, Bbl[j], acc[j]);
            acc[j] = MFMA32(Bal, Bbh[j], acc[j]);
        }
    }
    // epilogue: C[t][o] -> flat (h,l,d), add residual, scale, split, store in kattn frag order
#pragma unroll
    for (int j = 0; j < 2; ++j)
#pragma unroll
        for (int r = 0; r < 16; ++r) {
            int trow = tt * 64 + wm * 32 + (r & 3) + ((r >> 2) << 3) + (khalf << 2);
            int ocol = oTile * 128 + wn * 64 + j * 32 + lane31;
            int h = trow >> 8;
            int l = ((trow & 255) << 3) + (ocol >> 6);
            int d = ocol & 63;
            float v2 = (acc[j][r] + src[((size_t)h * Ll + l) * Dk + d]) * scale;
            f16 hi = (f16)v2;
            f16 lo = (f16)(v2 - (float)hi);
            size_t idx = ((((size_t)(b * 8 + h) * 64 + (l >> 5)) * 4 + (d >> 4)) * 64
                          + ((d >> 3) & 1) * 32 + (l & 31)) * 8 + (d & 7);
            dh[idx] = hi; dl[idx] = lo;
        }
}

// ---------------- F: fused attention, K-split across wave pairs ----------------
__global__ __launch_bounds__(256, 3) void kattn(
    const f16* __restrict__ qfh, const f16* __restrict__ qfl,
    const f16* __restrict__ kfh, const f16* __restrict__ kfl,
    const f16* __restrict__ vf,
    float* __restrict__ ctx_out, float* __restrict__ attn_out) {
    __shared__ float combuf[2][32][64];              // 16 KB exchange buffer
    __shared__ __align__(16) f16 ptile[4][32][40];   // 10 KB, 80B rows (16B-aligned b128 reads)
    int id = blockIdx.x;                             // 1024; 4 bh per XCD for K/V L2 locality
    int bh = (id & 7) * 4 + (id >> 8);
    int qt = (id >> 3) & 31;
    int wave = threadIdx.x >> 6, lane = threadIdx.x & 63;
    int qg = wave >> 1, kg = wave & 1;
    int lane31 = lane & 31, khalf = lane >> 5;
    int q0 = qt * 64 + qg * 32;

    // resident Q fragments (hi/lo): 4 ksteps of 16 over d_k=64, contiguous 1KB loads
    f16x8 a_h[4], a_l[4];
    {
        size_t qb = ((size_t)bh * 64 + qt * 2 + qg) * 4;
#pragma unroll
        for (int ks = 0; ks < 4; ++ks) {
            a_h[ks] = *(const f16x8*)(qfh + ((qb + ks) * 64 + lane) * 8);
            a_l[ks] = *(const f16x8*)(qfl + ((qb + ks) * 64 + lane) * 8);
        }
    }
    const f16* kbh = kfh + (size_t)bh * 131072;
    const f16* kbl = kfl + (size_t)bh * 131072;
    const int ch0 = kg * 32, ch1 = ch0 + 32;

    float m[16], s[16];
#pragma unroll
    for (int r = 0; r < 16; ++r) { m[r] = -3.0e38f; s[r] = 0.f; }

    // ---- pass 1: online row max + sum of 2^z over this wave's half of K ----
    for (int ch = ch0; ch < ch1; ++ch) {
        f32x16 acc;
#pragma unroll
        for (int r = 0; r < 16; ++r) acc[r] = 0.f;
        size_t kb = (size_t)ch * 2048 + lane * 8;
#pragma unroll
        for (int ks = 0; ks < 4; ++ks) {
            f16x8 kh8 = *(const f16x8*)(kbh + kb + ks * 512);
            f16x8 kl8 = *(const f16x8*)(kbl + kb + ks * 512);
            acc = MFMA32(a_h[ks], kh8, acc);
            acc = MFMA32(a_h[ks], kl8, acc);
            acc = MFMA32(a_l[ks], kh8, acc);
        }
#pragma unroll
        for (int r = 0; r < 16; ++r) {
            float v = acc[r];
            float d = v - m[r];
            float e = exp2f(-fabsf(d));
            bool gt = d > 0.f;
            s[r] = gt ? __fmaf_rn(s[r], e, 1.f) : (s[r] + e);
            m[r] = gt ? v : m[r];
        }
    }
    // lane combine within the 32 col-lanes of each half
#pragma unroll
    for (int r = 0; r < 16; ++r) {
        float mm = m[r], ss = s[r];
#pragma unroll
        for (int off = 1; off < 32; off <<= 1) {
            float mo = __shfl_xor(mm, off, 64);
            float so = __shfl_xor(ss, off, 64);
            float mn = fmaxf(mm, mo);
            ss = ss * exp2f(mm - mn) + so * exp2f(mo - mn);
            mm = mn;
        }
        m[r] = mm; s[r] = ss;
    }
    // cross-wave (k-split) combine through LDS
    if (kg == 1) {
#pragma unroll
        for (int r = 0; r < 16; ++r) {
            combuf[qg][r][lane] = m[r];
            combuf[qg][16 + r][lane] = s[r];
        }
    }
    __syncthreads();
    if (kg == 0) {
#pragma unroll
        for (int r = 0; r < 16; ++r) {
            float m1 = combuf[qg][r][lane];
            float s1 = combuf[qg][16 + r][lane];
            float mn = fmaxf(m[r], m1);
            float ss = s[r] * exp2f(m[r] - mn) + s1 * exp2f(m1 - mn);
            m[r] = mn; s[r] = 1.f / ss;
            combuf[qg][r][lane] = mn;
            combuf[qg][16 + r][lane] = s[r];
        }
    }
    __syncthreads();
    if (kg == 1) {
#pragma unroll
        for (int r = 0; r < 16; ++r) {
            m[r] = combuf[qg][r][lane];
            s[r] = combuf[qg][16 + r][lane];
        }
    }

    f32x16 ctx[2];
#pragma unroll
    for (int n = 0; n < 2; ++n)
#pragma unroll
        for (int r = 0; r < 16; ++r) ctx[n][r] = 0.f;

    const size_t rowbase = ((size_t)bh * Ll + q0 + lane31) * Ll;

    // ---- pass 2: recompute scores (identical op order), write attn, accumulate PV ----
    for (int ch = ch0; ch < ch1; ++ch) {
        f32x16 acc;
#pragma unroll
        for (int r = 0; r < 16; ++r) acc[r] = 0.f;
        size_t kb = (size_t)ch * 2048 + lane * 8;
#pragma unroll
        for (int ks = 0; ks < 4; ++ks) {
            f16x8 kh8 = *(const f16x8*)(kbh + kb + ks * 512);
            f16x8 kl8 = *(const f16x8*)(kbl + kb + ks * 512);
            acc = MFMA32(a_h[ks], kh8, acc);
            acc = MFMA32(a_h[ks], kl8, acc);
            acc = MFMA32(a_l[ks], kh8, acc);
        }
#pragma unroll
        for (int r = 0; r < 16; ++r) {
            float p = exp2f(acc[r] - m[r]) * s[r];
            int row = (r & 3) + ((r >> 2) << 3) + (khalf << 2);
            ptile[wave][row][lane31] = (f16)p;
        }
        __asm__ volatile("s_waitcnt lgkmcnt(0)" ::: "memory");  // wave-private LDS RAW
#pragma unroll
        for (int ks2 = 0; ks2 < 2; ++ks2) {
            f16x8 pa = *(const f16x8*)&ptile[wave][lane31][ks2 * 16 + khalf * 8];
            // attn store from the f16 tile: rows=lane31, 32B per lane, full-line coverage
            float* dst = attn_out + rowbase + ch * 32 + ks2 * 16 + khalf * 8;
            float4 v0 = {(float)pa[0], (float)pa[1], (float)pa[2], (float)pa[3]};
            float4 v1 = {(float)pa[4], (float)pa[5], (float)pa[6], (float)pa[7]};
            *(float4*)dst = v0;
            *(float4*)(dst + 4) = v1;
#pragma unroll
            for (int n = 0; n < 2; ++n) {
                size_t off = ((((size_t)bh * 2 + n) * 128 + ch * 2 + ks2) * 64 + lane) * 8;
                f16x8 vb = *(const f16x8*)(vf + off);
                ctx[n] = MFMA32(pa, vb, ctx[n]);
            }
        }
    }
    // ---- k-split ctx reduction ----
    __syncthreads();
    if (kg == 1) {
#pragma unroll
        for (int n = 0; n < 2; ++n)
#pragma unroll
            for (int r = 0; r < 16; ++r) combuf[qg][n * 16 + r][lane] = ctx[n][r];
    }
    __syncthreads();
    if (kg == 0) {
#pragma unroll
        for (int n = 0; n < 2; ++n)
#pragma unroll
            for (int r = 0; r < 16; ++r) {
                float v = ctx[n][r] + combuf[qg][n * 16 + r][lane];
                int row = (r & 3) + ((r >> 2) << 3) + (khalf << 2);
                ctx_out[((size_t)bh * Ll + q0 + row) * Dk + n * 32 + lane31] = v;
            }
    }
}

extern "C" void kernel_launch(void* const* d_in, const int* in_sizes, int n_in,
                              void* d_out, int out_size, void* d_ws, size_t ws_size,
                              hipStream_t stream) {
    const float* Q = (const float*)d_in[0];
    const float* K = (const float*)d_in[1];
    const float* V = (const float*)d_in[2];
    // d_in[3] = attn_mask (all-false, unused)
    const float* convq = (const float*)d_in[4];
    const float* convk = (const float*)d_in[5];
    const float* w = (const float*)d_in[6];

    char* ws = (char*)d_ws;
    int* flag = (int*)ws;
    f16* wfhq = (f16*)(ws + OFF_WF);
    f16* wflq = wfhq + NWF;
    f16* wfhk = wflq + NWF;
    f16* wflk = wfhk + NWF;
    f16* afhq = (f16*)(ws + OFF_AF);
    f16* aflq = afhq + NAF;
    f16* afhk = aflq + NAF;
    f16* aflk = afhk + NAF;
    f16* ffhq = (f16*)(ws + OFF_FF);
    f16* fflq = ffhq + NFF;
    f16* ffhk = fflq + NFF;
    f16* fflk = ffhk + NFF;
    f16* vf = (f16*)(ws + OFF_VF);

    float* ctx_out = (float*)d_out;
    float* attn_out = ctx_out + (size_t)BH * Ll * Dk;

    kprep_w<<<dim3(1024, 2), 256, 0, stream>>>(convq, convk, w, flag, wfhq, wflq, wfhk, wflk);
    kprep_v<<<dim3(16, 32), 256, 0, stream>>>(V, vf);
    kprep_a<<<dim3(2048, 4, 2), 256, 0, stream>>>(Q, K, flag, afhq, aflq, afhk, aflk);
    kconv<<<dim3(1024), 256, 0, stream>>>(Q, K, flag, afhq, aflq, afhk, aflk,
                                          wfhq, wflq, wfhk, wflk, ffhq, fflq, ffhk, fflk);
    kattn<<<dim3(1024), 256, 0, stream>>>(ffhq, fflq, ffhk, fflk, vf, ctx_out, attn_out);
}